// Round 27
// baseline (111.731 us; speedup 1.0000x reference)
//
#include <hip/hip_runtime.h>
#include <math.h>

#define NB 8
#define NC 192
#define NT 2048
#define NHALF 96
#define NP 29
#define OUT_ELEMS (NB*NC*NT)
#define KP 100    // staging LDS row stride in dwords (200 bf16, 192 used)
#define PR 129    // P LDS row stride in dwords ([t][m] bf16, 256 m + pad)

typedef short bf16x8 __attribute__((ext_vector_type(8)));
typedef float f32x4 __attribute__((ext_vector_type(4)));
typedef unsigned int u32x2 __attribute__((ext_vector_type(2)));
typedef unsigned int u32x4 __attribute__((ext_vector_type(4)));
typedef unsigned short u16;
typedef unsigned int u32;

__device__ __forceinline__ u16 f2bf(float f) {
    u32 u = __builtin_bit_cast(u32, f);
    u += 0x7fffu + ((u >> 16) & 1u);
    return (u16)(u >> 16);
}
// packed f32 pair -> 2x bf16 in one instruction (RNE, same as f2bf)
__device__ __forceinline__ u32 pk_bf16(float lo, float hi) {
    u32 r;
    asm("v_cvt_pk_bf16_f32 %0, %1, %2" : "=v"(r) : "v"(lo), "v"(hi));
    return r;
}
__device__ __forceinline__ float bf_lo(u32 w) { return __builtin_bit_cast(float, w << 16); }
__device__ __forceinline__ float bf_hi(u32 w) { return __builtin_bit_cast(float, w & 0xffff0000u); }
__device__ __forceinline__ float softplus_fast(float v) {
    return (v > 20.0f) ? v : __logf(1.0f + __expf(v));
}
// mish(x) = x*tanh(softplus(x)) = x*(s^2-1)/(s^2+1), s = 1+e^x
__device__ __forceinline__ float mishf(float v) {
    if (v > 20.0f) return v;
    float s = 1.0f + __expf(v);
    float s2 = s * s;
    return v * (s2 - 1.0f) / (s2 + 1.0f);
}

// ---------- weight convert + fragment swizzle ----------
// swz[tile*512 + lane*8 + e] = W[m][k], m = mt*16+(lane&15), k = kk*32+(lane>>4)*8+e
#define W1N 331776   // 3*3*36864
#define W2N 110592   // 3*36864
#define PADN 589824  // 1152*512
#define PREN 18432   // 36*512
#define WT2 (W1N+W2N+PADN+PREN)
__global__ __launch_bounds__(256) void wconv_kernel(
    const float* __restrict__ w1, const float* __restrict__ w2,
    const float* __restrict__ pjw, const float* __restrict__ pjb,
    const float* __restrict__ pw,
    u16* __restrict__ outw, float* __restrict__ pjb_pad)
{
    int i = blockIdx.x*256 + threadIdx.x;
    if (i < WT2) {
        float v;
        if (i < W1N) {
            int s = i / 110592, r = i % 110592;
            int j = r / 36864, q = r % 36864;
            int tile = q >> 9, lane = (q >> 3) & 63, e = q & 7;
            int mt = tile / 6, kk = tile % 6;
            int m = mt*16 + (lane & 15);
            int k = kk*32 + (lane >> 4)*8 + e;
            v = w1[(((size_t)s*192 + m)*192 + k)*3 + j];
        } else if (i < W1N + W2N) {
            int q0 = i - W1N;
            int s = q0 / 36864, q = q0 % 36864;
            int tile = q >> 9, lane = (q >> 3) & 63, e = q & 7;
            int mt = tile / 6, kk = tile % 6;
            int m = mt*16 + (lane & 15);
            int k = kk*32 + (lane >> 4)*8 + e;
            v = w2[((size_t)s*192 + m)*192 + k];
        } else if (i < W1N + W2N + PADN) {
            int q = i - W1N - W2N;
            int tile = q >> 9, lane = (q >> 3) & 63, e = q & 7;
            int mt = tile / 6, kk = tile % 6;
            int m = mt*16 + (lane & 15);            // 0..3071
            int k = kk*32 + (lane >> 4)*8 + e;
            int c = m >> 5, p = m & 31;
            v = (p < NP) ? pjw[((size_t)(c*NP + p))*192 + k] : 0.f;
        } else {
            int q = i - W1N - W2N - PADN;
            int tile = q >> 9, lane = (q >> 3) & 63, e = q & 7;
            int mt = tile / 3, kk = tile % 3;
            int m = mt*16 + (lane & 15);            // 0..191
            int k = kk*32 + (lane >> 4)*8 + e;      // 0..95
            v = pw[(size_t)m*96 + k];
        }
        outw[i] = f2bf(v);
    } else if (i < WT2 + 3072) {
        int mp = i - WT2;
        int c = mp >> 5, p = mp & 31;
        pjb_pad[mp] = (p < NP) ? pjb[c*NP + p] : 0.f;
    }
}

// ---------- prenet MFMA: hidB = bf16((W x0 + bias + cond) * mask) ----------
__global__ __launch_bounds__(256) void prenet_mfma_kernel(
    const float* __restrict__ x, const float* __restrict__ cond,
    const u16* __restrict__ wps, const float* __restrict__ bias,
    const float* __restrict__ masks, u32* __restrict__ hidB)
{
    __shared__ u32 sm[32 * 52];
    const int tid = threadIdx.x, lane = tid & 63, wid = tid >> 6;
    const int b = blockIdx.z, tg0 = blockIdx.x * 32;
    const int l15 = lane & 15, kg = lane >> 4;

    for (int idx = tid; idx < 48*32; idx += 256) {
        int c2 = idx >> 5, tl = idx & 31;
        const float* p = x + ((size_t)b*NC + 2*c2)*NT + tg0 + tl;
        sm[tl*52 + c2] = pk_bf16(p[0], p[NT]);
    }
    __syncthreads();

    // bias-init accumulators (MFMA C-in carries bias)
    f32x4 acc[3][2];
    #pragma unroll
    for (int ot = 0; ot < 3; ++ot) {
        f32x4 bi = *(const f32x4*)(bias + (wid*3 + ot)*16 + (kg << 2));
        acc[ot][0] = bi; acc[ot][1] = bi;
    }
    const char* smb = (const char*)sm;

    for (int kk = 0; kk < 3; ++kk) {
        int k0 = kk*32 + kg*8;
        bf16x8 b0 = *(const bf16x8*)(smb + (size_t)l15*208 + k0*2);
        bf16x8 b1f = *(const bf16x8*)(smb + (size_t)(l15+16)*208 + k0*2);
        bf16x8 af[3];
        #pragma unroll
        for (int ot = 0; ot < 3; ++ot) {
            int mt = wid*3 + ot;
            af[ot] = *(const bf16x8*)(wps + ((size_t)(mt*3 + kk))*512 + lane*8);
        }
        #pragma unroll
        for (int ot = 0; ot < 3; ++ot) {
            acc[ot][0] = __builtin_amdgcn_mfma_f32_16x16x32_bf16(af[ot], b0, acc[ot][0], 0, 0, 0);
            acc[ot][1] = __builtin_amdgcn_mfma_f32_16x16x32_bf16(af[ot], b1f, acc[ot][1], 0, 0, 0);
        }
    }

    #pragma unroll
    for (int ot = 0; ot < 3; ++ot) {
        int m = (wid*3 + ot)*16 + (kg << 2);
        #pragma unroll
        for (int tt = 0; tt < 2; ++tt) {
            int t = tg0 + tt*16 + l15;
            float mv = masks[(size_t)b*NT + t];
            f32x4 A = acc[ot][tt];
            f32x4 o;
            #pragma unroll
            for (int r = 0; r < 4; ++r)
                o[r] = (A[r] + cond[((size_t)b*NC + m + r)*NT + t]) * mv;
            *(u32x2*)(hidB + ((size_t)b*NT + t)*96 + (m >> 1)) =
                u32x2{pk_bf16(o[0], o[1]), pk_bf16(o[2], o[3])};
        }
    }
}

// ---------- fused residual block (TT=32, 512 threads, 8 waves) ----------
// wm = wid&3 owns 3 mt (48 m); wt = wid>>2 owns one 16-t half.
// hidM_new = hidM_old + mask * BN2(mish(conv2(BN1(mish(conv1(hidM))))))
template<int DIL>
__global__ __launch_bounds__(512) void resblock_kernel(
    const u32* __restrict__ hidBin, u32* __restrict__ hidBout,
    const u16* __restrict__ w1s, const u16* __restrict__ w2s,
    const float* __restrict__ masks,
    const float* __restrict__ b1v, const float* __restrict__ g1v, const float* __restrict__ bb1v,
    const float* __restrict__ bm1v, const float* __restrict__ bv1v,
    const float* __restrict__ b2v, const float* __restrict__ g2v, const float* __restrict__ bb2v,
    const float* __restrict__ bm2v, const float* __restrict__ bv2v)
{
    constexpr int ROWS = 32 + 2*DIL;
    __shared__ u32 sm1[ROWS * KP];
    __shared__ u32 sm2[32 * KP];
    const int tid = threadIdx.x, lane = tid & 63, wid = tid >> 6;
    const int wm = wid & 3, wt = wid >> 2;
    const int b = blockIdx.z, tg0 = blockIdx.x * 32;
    const int l15 = lane & 15, kg = lane >> 4;

    // stage pre-masked bf16 rows from hidBin: pure 16B copies
    for (int it = tid; it < ROWS*24; it += 512) {
        int row = it / 24, q = it - row*24;
        int t = tg0 + row - DIL;
        u32x4 v = u32x4{0,0,0,0};
        if (t >= 0 && t < NT)
            v = *(const u32x4*)(hidBin + ((size_t)b*NT + t)*96 + q*4);
        *(u32x4*)(&sm1[row*KP + q*4]) = v;
    }
    __syncthreads();

    // GEMM1 (bias-init acc), A-prefetch across 18 iters; 1 t-half per wave
    f32x4 acc[3];
    #pragma unroll
    for (int ot = 0; ot < 3; ++ot)
        acc[ot] = *(const f32x4*)(b1v + (wm*3 + ot)*16 + (kg << 2));
    const char* smb1 = (const char*)sm1;

    bf16x8 afc[3], afn[3];
    #pragma unroll
    for (int ot = 0; ot < 3; ++ot)
        afc[ot] = *(const bf16x8*)(w1s + ((size_t)((wm*3 + ot)*6))*512 + lane*8);

    #pragma unroll
    for (int it = 0; it < 18; ++it) {
        const int j = it / 6, kk = it % 6;
        if (it + 1 < 18) {
            const int jn = (it + 1) / 6, kkn = (it + 1) % 6;
            const u16* wn = w1s + (size_t)jn * 36864;
            #pragma unroll
            for (int ot = 0; ot < 3; ++ot)
                afn[ot] = *(const bf16x8*)(wn + ((size_t)((wm*3 + ot)*6 + kkn))*512 + lane*8);
        }
        int k0 = kk*32 + kg*8;
        bf16x8 b0 = *(const bf16x8*)(smb1 + (size_t)(wt*16 + l15 + j*DIL)*400 + k0*2);
        #pragma unroll
        for (int ot = 0; ot < 3; ++ot)
            acc[ot] = __builtin_amdgcn_mfma_f32_16x16x32_bf16(afc[ot], b0, acc[ot], 0, 0, 0);
        #pragma unroll
        for (int ot = 0; ot < 3; ++ot) afc[ot] = afn[ot];
    }

    // epilogue1: tmp = BN1(mish(acc)) -> sm2 [t][k] bf16 pairs
    #pragma unroll
    for (int ot = 0; ot < 3; ++ot) {
        int m = (wm*3 + ot)*16 + (kg << 2);
        f32x4 g4 = *(const f32x4*)(g1v + m);
        f32x4 bb4 = *(const f32x4*)(bb1v + m);
        f32x4 bm4 = *(const f32x4*)(bm1v + m);
        f32x4 bv4 = *(const f32x4*)(bv1v + m);
        int tl = wt*16 + l15;
        f32x4 A = acc[ot];
        float vr[4];
        #pragma unroll
        for (int r = 0; r < 4; ++r) {
            float v = mishf(A[r]);
            vr[r] = (v - bm4[r]) * (g4[r] * rsqrtf(bv4[r] + 1e-5f)) + bb4[r];
        }
        *(u32x2*)(&sm2[tl*KP + (m >> 1)]) = u32x2{pk_bf16(vr[0], vr[1]), pk_bf16(vr[2], vr[3])};
    }
    __syncthreads();

    // GEMM2 (bias-init acc), A-prefetch across 6 iters
    f32x4 acc2[3];
    #pragma unroll
    for (int ot = 0; ot < 3; ++ot)
        acc2[ot] = *(const f32x4*)(b2v + (wm*3 + ot)*16 + (kg << 2));
    const char* smb2 = (const char*)sm2;

    #pragma unroll
    for (int ot = 0; ot < 3; ++ot)
        afc[ot] = *(const bf16x8*)(w2s + ((size_t)((wm*3 + ot)*6))*512 + lane*8);

    #pragma unroll
    for (int kk = 0; kk < 6; ++kk) {
        if (kk + 1 < 6) {
            #pragma unroll
            for (int ot = 0; ot < 3; ++ot)
                afn[ot] = *(const bf16x8*)(w2s + ((size_t)((wm*3 + ot)*6 + kk + 1))*512 + lane*8);
        }
        int k0 = kk*32 + kg*8;
        bf16x8 b0 = *(const bf16x8*)(smb2 + (size_t)(wt*16 + l15)*400 + k0*2);
        #pragma unroll
        for (int ot = 0; ot < 3; ++ot)
            acc2[ot] = __builtin_amdgcn_mfma_f32_16x16x32_bf16(afc[ot], b0, acc2[ot], 0, 0, 0);
        #pragma unroll
        for (int ot = 0; ot < 3; ++ot) afc[ot] = afn[ot];
    }

    // epilogue2: hidBout = bf16(old(sm1) + mask * BN2(mish(acc2)))
    #pragma unroll
    for (int ot = 0; ot < 3; ++ot) {
        int m = (wm*3 + ot)*16 + (kg << 2);
        f32x4 g4 = *(const f32x4*)(g2v + m);
        f32x4 bb4 = *(const f32x4*)(bb2v + m);
        f32x4 bm4 = *(const f32x4*)(bm2v + m);
        f32x4 bv4 = *(const f32x4*)(bv2v + m);
        int tl = wt*16 + l15;
        int t = tg0 + tl;
        float mv = masks[(size_t)b*NT + t];
        f32x4 A = acc2[ot];
        u32x2 ow = *(const u32x2*)(&sm1[(tl + DIL)*KP + (m >> 1)]);
        float old0 = bf_lo(ow[0]), old1 = bf_hi(ow[0]);
        float old2 = bf_lo(ow[1]), old3 = bf_hi(ow[1]);
        float nv[4];
        {
            float v0 = mishf(A[0]), v1 = mishf(A[1]), v2 = mishf(A[2]), v3 = mishf(A[3]);
            nv[0] = old0 + mv * ((v0 - bm4[0]) * (g4[0] * rsqrtf(bv4[0] + 1e-5f)) + bb4[0]);
            nv[1] = old1 + mv * ((v1 - bm4[1]) * (g4[1] * rsqrtf(bv4[1] + 1e-5f)) + bb4[1]);
            nv[2] = old2 + mv * ((v2 - bm4[2]) * (g4[2] * rsqrtf(bv4[2] + 1e-5f)) + bb4[2]);
            nv[3] = old3 + mv * ((v3 - bm4[3]) * (g4[3] * rsqrtf(bv4[3] + 1e-5f)) + bb4[3]);
        }
        *(u32x2*)(hidBout + ((size_t)b*NT + t)*96 + (m >> 1)) =
            u32x2{pk_bf16(nv[0], nv[1]), pk_bf16(nv[2], nv[3])};
    }
}

// ---------- fused proj GEMM (M=256/block, 8 waves x 2mt) + RQ spline ----------
// grid (16 t-tiles, 12 m-blocks(=8c each), 16 units(b,th)), block 512
__global__ __launch_bounds__(512) void proj_spline_mfma_kernel(
    const u32* __restrict__ hidB, const u16* __restrict__ wpad,
    const float* __restrict__ pjb_pad, const float* __restrict__ x,
    const float* __restrict__ masks, float* __restrict__ outp,
    float* __restrict__ partial)
{
    __shared__ u32 uls[64*PR];   // union: staging [64][KP] then P [64 t][258 u16]
    __shared__ float red8[8];
    const int tid  = threadIdx.x;
    const int lane = tid & 63;
    const int wid  = tid >> 6;   // 0..7
    const int z  = blockIdx.z;
    const int b  = z >> 1, th = z & 1;
    const int tg0 = th*1024 + blockIdx.x*64;
    const int l15 = lane & 15;
    const int kg  = lane >> 4;

    // ---- stage B tile: pre-masked bf16 from hidB, pure 16B copies ----
    for (int it = tid; it < 64*24; it += 512) {
        int row = it / 24, q = it - row*24;
        u32x4 v = *(const u32x4*)(hidB + ((size_t)b*NT + tg0 + row)*96 + q*4);
        *(u32x4*)(&uls[row*KP + q*4]) = v;
    }
    __syncthreads();

    // ---- GEMM: 256 m x 64 t x 192 k, 8 waves each own 2 mt ----
    f32x4 acc[2][4];   // [ot][tt]
    #pragma unroll
    for (int ot = 0; ot < 2; ++ot) {
        f32x4 pb = *(const f32x4*)(pjb_pad + blockIdx.y*256 + (wid*2 + ot)*16 + (kg << 2));
        #pragma unroll
        for (int tt = 0; tt < 4; ++tt) acc[ot][tt] = pb;
    }
    const char* smb = (const char*)uls;

    for (int kk = 0; kk < 6; ++kk) {
        int k0 = kk*32 + kg*8;
        bf16x8 bt[4];
        #pragma unroll
        for (int tt = 0; tt < 4; ++tt)
            bt[tt] = *(const bf16x8*)(smb + (size_t)(tt*16 + l15)*400 + k0*2);
        bf16x8 af[2];
        #pragma unroll
        for (int ot = 0; ot < 2; ++ot) {
            int mt = blockIdx.y*16 + wid*2 + ot;
            af[ot] = *(const bf16x8*)(wpad + ((size_t)(mt*6 + kk))*512 + lane*8);
        }
        #pragma unroll
        for (int ot = 0; ot < 2; ++ot)
            #pragma unroll
            for (int tt = 0; tt < 4; ++tt)
                acc[ot][tt] = __builtin_amdgcn_mfma_f32_16x16x32_bf16(af[ot], bt[tt], acc[ot][tt], 0, 0, 0);
    }
    __syncthreads();   // staging dead; reuse LDS as P [t][m] bf16

    // ---- P[t][mloc] = bf16(acc*mask), cvt_pk + u32x2 stores ----
    #pragma unroll
    for (int tt = 0; tt < 4; ++tt) {
        int t = tt*16 + l15;
        float mkv = masks[(size_t)b*NT + tg0 + t];
        #pragma unroll
        for (int ot = 0; ot < 2; ++ot) {
            int mloc = (wid*2 + ot)*16 + (kg << 2);
            f32x4 A = acc[ot][tt];
            *(u32x2*)(&uls[t*PR + (mloc >> 1)]) =
                u32x2{pk_bf16(A[0]*mkv, A[1]*mkv), pk_bf16(A[2]*mkv, A[3]*mkv)};
        }
    }
    __syncthreads();

    // ---- spline: 8 c-channels x 64 t = 512 items, exactly 1 per thread ----
    float lsum = 0.f;
    {
        int cl = tid >> 6, t = tid & 63;
        int c  = blockIdx.y*8 + cl;
        int tg = tg0 + t;
        float m = masks[(size_t)b*NT + tg];

        // x0 flip copy
        float x0v = x[((size_t)b*NC + c)*NT + tg];
        outp[((size_t)b*NC + (NC-1 - c))*NT + tg] = x0v * m;

        float pr[30];
        #pragma unroll
        for (int j = 0; j < 15; ++j) {
            u32 w = uls[t*PR + cl*16 + j];
            pr[2*j]   = bf_lo(w);
            pr[2*j+1] = bf_hi(w);
        }

        float x1 = x[((size_t)b*NC + NHALF + c)*NT + tg];
        float xc = fminf(fmaxf(x1, -5.f), 5.f);

        // exp2 constant-fold: exp(pr*invsq) = exp2(pr * invsq*log2e)
        const float C = 0.10412020934368074f;  // (1/sqrt(192)) * log2(e)
        float ew[10], eh[10], sw = 0.f, sh = 0.f;
        #pragma unroll
        for (int i = 0; i < 10; ++i) { ew[i] = __builtin_amdgcn_exp2f(pr[i]    * C); sw += ew[i]; }
        #pragma unroll
        for (int i = 0; i < 10; ++i) { eh[i] = __builtin_amdgcn_exp2f(pr[10+i] * C); sh += eh[i]; }
        float isw = __builtin_amdgcn_rcpf(sw) * 9.9f;   // step = 0.01 + 9.9*e*inv_s
        float ish = __builtin_amdgcn_rcpf(sh) * 9.9f;

        // fused cumsum + knot selection (forced endpoints preserved)
        float cwp = -5.f, chp = -5.f;
        float icw = -5.f, ich = -5.f, iw = 0.f, ih = 0.f;
        float s0 = 0.f, s1 = pr[20], f0 = 1.f, f9 = 0.f;
        #pragma unroll
        for (int i = 0; i < 10; ++i) {
            float stepw = 0.01f + ew[i]*isw;
            float steph = 0.01f + eh[i]*ish;
            if (i == 9) { stepw = 5.f - cwp; steph = 5.f - chp; }  // forced cw[10]=5
            if (i == 0) {
                iw = stepw; ih = steph;
            } else {
                bool ge = (xc >= cwp);
                icw = ge ? cwp   : icw;
                iw  = ge ? stepw : iw;
                ich = ge ? chp   : ich;
                ih  = ge ? steph : ih;
                s0  = ge ? pr[19+i] : s0;
                if (i <= 8) s1 = ge ? pr[20+i] : s1;
                f0  = ge ? 0.f : f0;
                if (i == 9) f9 = ge ? 1.f : 0.f;
            }
            cwp += stepw; chp += steph;
        }
        float d0 = (f0 != 0.f) ? 1.f : 0.001f + softplus_fast(s0);
        float d1 = (f9 != 0.f) ? 1.f : 0.001f + softplus_fast(s1);

        float rw    = __builtin_amdgcn_rcpf(iw);
        float dlt   = ih * rw;
        float theta = (xc - icw) * rw;
        float t1m   = theta * (1.f - theta);
        float den   = dlt + (d0 + d1 - 2.f*dlt) * t1m;
        float rden  = __builtin_amdgcn_rcpf(den);
        float num   = ih * (dlt*theta*theta + d0*t1m);
        float outv  = ich + num * rden;
        float omt   = 1.f - theta;
        float dnum  = dlt*dlt*(d1*theta*theta + 2.f*dlt*t1m + d0*omt*omt);
        float lad   = __logf(dnum * rden * rden);
        bool inside = (x1 >= -5.f) && (x1 <= 5.f);
        float xout  = inside ? outv : x1;
        float ladv  = inside ? lad : 0.f;
        outp[((size_t)b*NC + (NHALF-1 - c))*NT + tg] = xout * m;
        lsum = ladv * m;
    }

    // ---- wave-shuffle reduction, then 8-way cross-wave sum ----
    #pragma unroll
    for (int off = 32; off > 0; off >>= 1)
        lsum += __shfl_down(lsum, off, 64);
    if (lane == 0) red8[wid] = lsum;
    __syncthreads();
    if (tid == 0) {
        float s = 0.f;
        #pragma unroll
        for (int i = 0; i < 8; ++i) s += red8[i];
        partial[(size_t)b*384 + th*192 + blockIdx.y*16 + blockIdx.x] = s;
    }
}

__global__ __launch_bounds__(256) void logdet_reduce_kernel(
    const float* __restrict__ partial, float* __restrict__ outp)
{
    __shared__ float red[256];
    const int b = blockIdx.x;
    const int tid = threadIdx.x;
    float s = 0.f;
    for (int i = tid; i < 384; i += 256) s += partial[(size_t)b*384 + i];
    red[tid] = s;
    __syncthreads();
    for (int st = 128; st > 0; st >>= 1) {
        if (tid < st) red[tid] += red[tid + st];
        __syncthreads();
    }
    if (tid == 0) outp[(size_t)OUT_ELEMS + b] = red[0];
}

extern "C" void kernel_launch(void* const* d_in, const int* in_sizes, int n_in,
                              void* d_out, int out_size, void* d_ws, size_t ws_size,
                              hipStream_t stream) {
    const float* x     = (const float*)d_in[0];
    const float* cond  = (const float*)d_in[1];
    const float* masks = (const float*)d_in[2];
    const float* pw    = (const float*)d_in[3];
    const float* pb    = (const float*)d_in[4];
    const float* w1    = (const float*)d_in[5];
    const float* b1    = (const float*)d_in[6];
    const float* g1    = (const float*)d_in[7];
    const float* bb1   = (const float*)d_in[8];
    const float* m1    = (const float*)d_in[9];
    const float* v1    = (const float*)d_in[10];
    const float* w2    = (const float*)d_in[11];
    const float* b2    = (const float*)d_in[12];
    const float* g2    = (const float*)d_in[13];
    const float* bb2   = (const float*)d_in[14];
    const float* m2    = (const float*)d_in[15];
    const float* v2    = (const float*)d_in[16];
    const float* pjw   = (const float*)d_in[17];
    const float* pjb   = (const float*)d_in[18];

    float* out = (float*)d_out;
    char* wsb = (char*)d_ws;
    u32*   hidB0   = (u32*)wsb;                                    //  6,291,456 B
    u32*   hidB1   = (u32*)(wsb + 6291456);                        //  6,291,456 B
    u16*   wbf     = (u16*)(wsb + 12582912);                       //  2,101,248 B
    float* pjb_pad = (float*)(wsb + 12582912 + 2101248);           //     12,288 B
    float* partial = (float*)(wsb + 12582912 + 2101248 + 12288);   //     16,384 B

    dim3 blk(256);

    wconv_kernel<<<dim3((WT2 + 3072 + 255)/256), blk, 0, stream>>>(
        w1, w2, pjw, pjb, pw, wbf, pjb_pad);

    const u16* preswz = wbf + W1N + W2N + PADN;
    prenet_mfma_kernel<<<dim3(64,1,8), blk, 0, stream>>>(
        x, cond, preswz, pb, masks, hidB0);

    dim3 grid_r(64, 1, 8);
    {
        resblock_kernel<1><<<grid_r, dim3(512), 0, stream>>>(hidB0, hidB1, wbf, wbf + W1N, masks,
            b1, g1, bb1, m1, v1, b2, g2, bb2, m2, v2);
    }
    {
        const u16* w1l = wbf + (size_t)1*110592;
        const u16* w2l = wbf + W1N + (size_t)1*36864;
        resblock_kernel<3><<<grid_r, dim3(512), 0, stream>>>(hidB1, hidB0, w1l, w2l, masks,
            b1+NC, g1+NC, bb1+NC, m1+NC, v1+NC, b2+NC, g2+NC, bb2+NC, m2+NC, v2+NC);
    }
    {
        const u16* w1l = wbf + (size_t)2*110592;
        const u16* w2l = wbf + W1N + (size_t)2*36864;
        resblock_kernel<9><<<grid_r, dim3(512), 0, stream>>>(hidB0, hidB1, w1l, w2l, masks,
            b1+2*NC, g1+2*NC, bb1+2*NC, m1+2*NC, v1+2*NC,
            b2+2*NC, g2+2*NC, bb2+2*NC, m2+2*NC, v2+2*NC);
    }

    const u16* pjwpad = wbf + W1N + W2N;
    proj_spline_mfma_kernel<<<dim3(16,12,16), dim3(512), 0, stream>>>(
        hidB1, pjwpad, pjb_pad, x, masks, out, partial);

    logdet_reduce_kernel<<<dim3(8), blk, 0, stream>>>(partial, out);
}

// Round 28
// 105.244 us; speedup vs baseline: 1.0616x; 1.0616x over previous
//
#include <hip/hip_runtime.h>
#include <math.h>

#define NB 8
#define NC 192
#define NT 2048
#define NHALF 96
#define NP 29
#define OUT_ELEMS (NB*NC*NT)
#define KP 100    // staging LDS row stride in dwords (200 bf16, 192 used)
#define PR 129    // P LDS row stride in dwords ([t][m] bf16, 256 m + pad)

typedef short bf16x8 __attribute__((ext_vector_type(8)));
typedef float f32x4 __attribute__((ext_vector_type(4)));
typedef unsigned int u32x2 __attribute__((ext_vector_type(2)));
typedef unsigned int u32x4 __attribute__((ext_vector_type(4)));
typedef unsigned short u16;
typedef unsigned int u32;

__device__ __forceinline__ u16 f2bf(float f) {
    u32 u = __builtin_bit_cast(u32, f);
    u += 0x7fffu + ((u >> 16) & 1u);
    return (u16)(u >> 16);
}
// packed f32 pair -> 2x bf16 in one instruction (RNE, same as f2bf)
__device__ __forceinline__ u32 pk_bf16(float lo, float hi) {
    u32 r;
    asm("v_cvt_pk_bf16_f32 %0, %1, %2" : "=v"(r) : "v"(lo), "v"(hi));
    return r;
}
__device__ __forceinline__ float bf_lo(u32 w) { return __builtin_bit_cast(float, w << 16); }
__device__ __forceinline__ float bf_hi(u32 w) { return __builtin_bit_cast(float, w & 0xffff0000u); }
__device__ __forceinline__ float softplus_fast(float v) {
    return (v > 20.0f) ? v : __logf(1.0f + __expf(v));
}
// mish(x) = x*tanh(softplus(x)) = x*(s^2-1)/(s^2+1), s = 1+e^x
__device__ __forceinline__ float mishf(float v) {
    if (v > 20.0f) return v;
    float s = 1.0f + __expf(v);
    float s2 = s * s;
    return v * (s2 - 1.0f) / (s2 + 1.0f);
}

// ---------- weight convert + fragment swizzle ----------
// swz[tile*512 + lane*8 + e] = W[m][k], m = mt*16+(lane&15), k = kk*32+(lane>>4)*8+e
#define W1N 331776   // 3*3*36864
#define W2N 110592   // 3*36864
#define PADN 589824  // 1152*512
#define PREN 18432   // 36*512
#define WT2 (W1N+W2N+PADN+PREN)
__global__ __launch_bounds__(256) void wconv_kernel(
    const float* __restrict__ w1, const float* __restrict__ w2,
    const float* __restrict__ pjw, const float* __restrict__ pjb,
    const float* __restrict__ pw,
    u16* __restrict__ outw, float* __restrict__ pjb_pad)
{
    int i = blockIdx.x*256 + threadIdx.x;
    if (i < WT2) {
        float v;
        if (i < W1N) {
            int s = i / 110592, r = i % 110592;
            int j = r / 36864, q = r % 36864;
            int tile = q >> 9, lane = (q >> 3) & 63, e = q & 7;
            int mt = tile / 6, kk = tile % 6;
            int m = mt*16 + (lane & 15);
            int k = kk*32 + (lane >> 4)*8 + e;
            v = w1[(((size_t)s*192 + m)*192 + k)*3 + j];
        } else if (i < W1N + W2N) {
            int q0 = i - W1N;
            int s = q0 / 36864, q = q0 % 36864;
            int tile = q >> 9, lane = (q >> 3) & 63, e = q & 7;
            int mt = tile / 6, kk = tile % 6;
            int m = mt*16 + (lane & 15);
            int k = kk*32 + (lane >> 4)*8 + e;
            v = w2[((size_t)s*192 + m)*192 + k];
        } else if (i < W1N + W2N + PADN) {
            int q = i - W1N - W2N;
            int tile = q >> 9, lane = (q >> 3) & 63, e = q & 7;
            int mt = tile / 6, kk = tile % 6;
            int m = mt*16 + (lane & 15);            // 0..3071
            int k = kk*32 + (lane >> 4)*8 + e;
            int c = m >> 5, p = m & 31;
            v = (p < NP) ? pjw[((size_t)(c*NP + p))*192 + k] : 0.f;
        } else {
            int q = i - W1N - W2N - PADN;
            int tile = q >> 9, lane = (q >> 3) & 63, e = q & 7;
            int mt = tile / 3, kk = tile % 3;
            int m = mt*16 + (lane & 15);            // 0..191
            int k = kk*32 + (lane >> 4)*8 + e;      // 0..95
            v = pw[(size_t)m*96 + k];
        }
        outw[i] = f2bf(v);
    } else if (i < WT2 + 3072) {
        int mp = i - WT2;
        int c = mp >> 5, p = mp & 31;
        pjb_pad[mp] = (p < NP) ? pjb[c*NP + p] : 0.f;
    }
}

// ---------- prenet MFMA: hidB = bf16((W x0 + bias + cond) * mask) ----------
__global__ __launch_bounds__(256) void prenet_mfma_kernel(
    const float* __restrict__ x, const float* __restrict__ cond,
    const u16* __restrict__ wps, const float* __restrict__ bias,
    const float* __restrict__ masks, u32* __restrict__ hidB)
{
    __shared__ u32 sm[32 * 52];
    const int tid = threadIdx.x, lane = tid & 63, wid = tid >> 6;
    const int b = blockIdx.z, tg0 = blockIdx.x * 32;
    const int l15 = lane & 15, kg = lane >> 4;

    for (int idx = tid; idx < 48*32; idx += 256) {
        int c2 = idx >> 5, tl = idx & 31;
        const float* p = x + ((size_t)b*NC + 2*c2)*NT + tg0 + tl;
        sm[tl*52 + c2] = pk_bf16(p[0], p[NT]);
    }
    __syncthreads();

    // bias-init accumulators (MFMA C-in carries bias)
    f32x4 acc[3][2];
    #pragma unroll
    for (int ot = 0; ot < 3; ++ot) {
        f32x4 bi = *(const f32x4*)(bias + (wid*3 + ot)*16 + (kg << 2));
        acc[ot][0] = bi; acc[ot][1] = bi;
    }
    const char* smb = (const char*)sm;

    for (int kk = 0; kk < 3; ++kk) {
        int k0 = kk*32 + kg*8;
        bf16x8 b0 = *(const bf16x8*)(smb + (size_t)l15*208 + k0*2);
        bf16x8 b1f = *(const bf16x8*)(smb + (size_t)(l15+16)*208 + k0*2);
        bf16x8 af[3];
        #pragma unroll
        for (int ot = 0; ot < 3; ++ot) {
            int mt = wid*3 + ot;
            af[ot] = *(const bf16x8*)(wps + ((size_t)(mt*3 + kk))*512 + lane*8);
        }
        #pragma unroll
        for (int ot = 0; ot < 3; ++ot) {
            acc[ot][0] = __builtin_amdgcn_mfma_f32_16x16x32_bf16(af[ot], b0, acc[ot][0], 0, 0, 0);
            acc[ot][1] = __builtin_amdgcn_mfma_f32_16x16x32_bf16(af[ot], b1f, acc[ot][1], 0, 0, 0);
        }
    }

    #pragma unroll
    for (int ot = 0; ot < 3; ++ot) {
        int m = (wid*3 + ot)*16 + (kg << 2);
        #pragma unroll
        for (int tt = 0; tt < 2; ++tt) {
            int t = tg0 + tt*16 + l15;
            float mv = masks[(size_t)b*NT + t];
            f32x4 A = acc[ot][tt];
            f32x4 o;
            #pragma unroll
            for (int r = 0; r < 4; ++r)
                o[r] = (A[r] + cond[((size_t)b*NC + m + r)*NT + t]) * mv;
            *(u32x2*)(hidB + ((size_t)b*NT + t)*96 + (m >> 1)) =
                u32x2{pk_bf16(o[0], o[1]), pk_bf16(o[2], o[3])};
        }
    }
}

// ---------- fused residual block (TT=32), bf16 masked trunk ----------
// hidM_new = hidM_old + mask * BN2(mish(conv2(BN1(mish(conv1(hidM))))))
// old value comes from sm1 (already staged) -- no global trunk RMW.
template<int DIL>
__global__ __launch_bounds__(256) void resblock_kernel(
    const u32* __restrict__ hidBin, u32* __restrict__ hidBout,
    const u16* __restrict__ w1s, const u16* __restrict__ w2s,
    const float* __restrict__ masks,
    const float* __restrict__ b1v, const float* __restrict__ g1v, const float* __restrict__ bb1v,
    const float* __restrict__ bm1v, const float* __restrict__ bv1v,
    const float* __restrict__ b2v, const float* __restrict__ g2v, const float* __restrict__ bb2v,
    const float* __restrict__ bm2v, const float* __restrict__ bv2v)
{
    constexpr int ROWS = 32 + 2*DIL;
    __shared__ u32 sm1[ROWS * KP];
    __shared__ u32 sm2[32 * KP];
    const int tid = threadIdx.x, lane = tid & 63, wid = tid >> 6;
    const int b = blockIdx.z, tg0 = blockIdx.x * 32;
    const int l15 = lane & 15, kg = lane >> 4;

    // stage pre-masked bf16 rows from hidBin: pure 16B copies
    for (int it = tid; it < ROWS*24; it += 256) {
        int row = it / 24, q = it - row*24;
        int t = tg0 + row - DIL;
        u32x4 v = u32x4{0,0,0,0};
        if (t >= 0 && t < NT)
            v = *(const u32x4*)(hidBin + ((size_t)b*NT + t)*96 + q*4);
        *(u32x4*)(&sm1[row*KP + q*4]) = v;
    }
    __syncthreads();

    // GEMM1 (bias-init acc), A-prefetch across 18 iters
    f32x4 acc[3][2];
    #pragma unroll
    for (int ot = 0; ot < 3; ++ot) {
        f32x4 bi = *(const f32x4*)(b1v + (wid*3 + ot)*16 + (kg << 2));
        acc[ot][0] = bi; acc[ot][1] = bi;
    }
    const char* smb1 = (const char*)sm1;

    bf16x8 afc[3], afn[3];
    #pragma unroll
    for (int ot = 0; ot < 3; ++ot)
        afc[ot] = *(const bf16x8*)(w1s + ((size_t)((wid*3 + ot)*6))*512 + lane*8);

    #pragma unroll
    for (int it = 0; it < 18; ++it) {
        const int j = it / 6, kk = it % 6;
        if (it + 1 < 18) {
            const int jn = (it + 1) / 6, kkn = (it + 1) % 6;
            const u16* wn = w1s + (size_t)jn * 36864;
            #pragma unroll
            for (int ot = 0; ot < 3; ++ot)
                afn[ot] = *(const bf16x8*)(wn + ((size_t)((wid*3 + ot)*6 + kkn))*512 + lane*8);
        }
        int k0 = kk*32 + kg*8;
        bf16x8 b0  = *(const bf16x8*)(smb1 + (size_t)(l15 + j*DIL)*400 + k0*2);
        bf16x8 b1f = *(const bf16x8*)(smb1 + (size_t)(l15 + 16 + j*DIL)*400 + k0*2);
        #pragma unroll
        for (int ot = 0; ot < 3; ++ot) {
            acc[ot][0] = __builtin_amdgcn_mfma_f32_16x16x32_bf16(afc[ot], b0,  acc[ot][0], 0, 0, 0);
            acc[ot][1] = __builtin_amdgcn_mfma_f32_16x16x32_bf16(afc[ot], b1f, acc[ot][1], 0, 0, 0);
        }
        #pragma unroll
        for (int ot = 0; ot < 3; ++ot) afc[ot] = afn[ot];
    }

    // epilogue1: tmp = BN1(mish(acc)) -> sm2 [t][k] bf16 pairs
    #pragma unroll
    for (int ot = 0; ot < 3; ++ot) {
        int m = (wid*3 + ot)*16 + (kg << 2);
        f32x4 g4 = *(const f32x4*)(g1v + m);
        f32x4 bb4 = *(const f32x4*)(bb1v + m);
        f32x4 bm4 = *(const f32x4*)(bm1v + m);
        f32x4 bv4 = *(const f32x4*)(bv1v + m);
        #pragma unroll
        for (int tt = 0; tt < 2; ++tt) {
            int tl = tt*16 + l15;
            f32x4 A = acc[ot][tt];
            float vr[4];
            #pragma unroll
            for (int r = 0; r < 4; ++r) {
                float v = mishf(A[r]);
                vr[r] = (v - bm4[r]) * (g4[r] * rsqrtf(bv4[r] + 1e-5f)) + bb4[r];
            }
            *(u32x2*)(&sm2[tl*KP + (m >> 1)]) = u32x2{pk_bf16(vr[0], vr[1]), pk_bf16(vr[2], vr[3])};
        }
    }
    __syncthreads();

    // GEMM2 (bias-init acc), A-prefetch across 6 iters
    f32x4 acc2[3][2];
    #pragma unroll
    for (int ot = 0; ot < 3; ++ot) {
        f32x4 bi = *(const f32x4*)(b2v + (wid*3 + ot)*16 + (kg << 2));
        acc2[ot][0] = bi; acc2[ot][1] = bi;
    }
    const char* smb2 = (const char*)sm2;

    #pragma unroll
    for (int ot = 0; ot < 3; ++ot)
        afc[ot] = *(const bf16x8*)(w2s + ((size_t)((wid*3 + ot)*6))*512 + lane*8);

    #pragma unroll
    for (int kk = 0; kk < 6; ++kk) {
        if (kk + 1 < 6) {
            #pragma unroll
            for (int ot = 0; ot < 3; ++ot)
                afn[ot] = *(const bf16x8*)(w2s + ((size_t)((wid*3 + ot)*6 + kk + 1))*512 + lane*8);
        }
        int k0 = kk*32 + kg*8;
        bf16x8 b0  = *(const bf16x8*)(smb2 + (size_t)l15*400 + k0*2);
        bf16x8 b1f = *(const bf16x8*)(smb2 + (size_t)(l15+16)*400 + k0*2);
        #pragma unroll
        for (int ot = 0; ot < 3; ++ot) {
            acc2[ot][0] = __builtin_amdgcn_mfma_f32_16x16x32_bf16(afc[ot], b0,  acc2[ot][0], 0, 0, 0);
            acc2[ot][1] = __builtin_amdgcn_mfma_f32_16x16x32_bf16(afc[ot], b1f, acc2[ot][1], 0, 0, 0);
        }
        #pragma unroll
        for (int ot = 0; ot < 3; ++ot) afc[ot] = afn[ot];
    }

    // epilogue2: hidBout = bf16(old(sm1) + mask * BN2(mish(acc2)))
    #pragma unroll
    for (int ot = 0; ot < 3; ++ot) {
        int m = (wid*3 + ot)*16 + (kg << 2);
        f32x4 g4 = *(const f32x4*)(g2v + m);
        f32x4 bb4 = *(const f32x4*)(bb2v + m);
        f32x4 bm4 = *(const f32x4*)(bm2v + m);
        f32x4 bv4 = *(const f32x4*)(bv2v + m);
        #pragma unroll
        for (int tt = 0; tt < 2; ++tt) {
            int tl = tt*16 + l15;
            int t = tg0 + tl;
            float mv = masks[(size_t)b*NT + t];
            f32x4 A = acc2[ot][tt];
            u32x2 ow = *(const u32x2*)(&sm1[(tl + DIL)*KP + (m >> 1)]);
            float old0 = bf_lo(ow[0]), old1 = bf_hi(ow[0]);
            float old2 = bf_lo(ow[1]), old3 = bf_hi(ow[1]);
            float nv[4];
            {
                float v0 = mishf(A[0]), v1 = mishf(A[1]), v2 = mishf(A[2]), v3 = mishf(A[3]);
                nv[0] = old0 + mv * ((v0 - bm4[0]) * (g4[0] * rsqrtf(bv4[0] + 1e-5f)) + bb4[0]);
                nv[1] = old1 + mv * ((v1 - bm4[1]) * (g4[1] * rsqrtf(bv4[1] + 1e-5f)) + bb4[1]);
                nv[2] = old2 + mv * ((v2 - bm4[2]) * (g4[2] * rsqrtf(bv4[2] + 1e-5f)) + bb4[2]);
                nv[3] = old3 + mv * ((v3 - bm4[3]) * (g4[3] * rsqrtf(bv4[3] + 1e-5f)) + bb4[3]);
            }
            *(u32x2*)(hidBout + ((size_t)b*NT + t)*96 + (m >> 1)) =
                u32x2{pk_bf16(nv[0], nv[1]), pk_bf16(nv[2], nv[3])};
        }
    }
}

// ---------- fused proj GEMM (M=256/block, 8 waves x 2mt) + RQ spline ----------
// grid (16 t-tiles, 12 m-blocks(=8c each), 16 units(b,th)), block 512
__global__ __launch_bounds__(512) void proj_spline_mfma_kernel(
    const u32* __restrict__ hidB, const u16* __restrict__ wpad,
    const float* __restrict__ pjb_pad, const float* __restrict__ x,
    const float* __restrict__ masks, float* __restrict__ outp,
    float* __restrict__ partial)
{
    __shared__ u32 uls[64*PR];   // union: staging [64][KP] then P [64 t][258 u16]
    __shared__ float red8[8];
    const int tid  = threadIdx.x;
    const int lane = tid & 63;
    const int wid  = tid >> 6;   // 0..7
    const int z  = blockIdx.z;
    const int b  = z >> 1, th = z & 1;
    const int tg0 = th*1024 + blockIdx.x*64;
    const int l15 = lane & 15;
    const int kg  = lane >> 4;

    // ---- stage B tile: pre-masked bf16 from hidB, pure 16B copies ----
    for (int it = tid; it < 64*24; it += 512) {
        int row = it / 24, q = it - row*24;
        u32x4 v = *(const u32x4*)(hidB + ((size_t)b*NT + tg0 + row)*96 + q*4);
        *(u32x4*)(&uls[row*KP + q*4]) = v;
    }
    __syncthreads();

    // ---- GEMM: 256 m x 64 t x 192 k, 8 waves each own 2 mt ----
    f32x4 acc[2][4];   // [ot][tt]
    #pragma unroll
    for (int ot = 0; ot < 2; ++ot) {
        f32x4 pb = *(const f32x4*)(pjb_pad + blockIdx.y*256 + (wid*2 + ot)*16 + (kg << 2));
        #pragma unroll
        for (int tt = 0; tt < 4; ++tt) acc[ot][tt] = pb;
    }
    const char* smb = (const char*)uls;

    for (int kk = 0; kk < 6; ++kk) {
        int k0 = kk*32 + kg*8;
        bf16x8 bt[4];
        #pragma unroll
        for (int tt = 0; tt < 4; ++tt)
            bt[tt] = *(const bf16x8*)(smb + (size_t)(tt*16 + l15)*400 + k0*2);
        bf16x8 af[2];
        #pragma unroll
        for (int ot = 0; ot < 2; ++ot) {
            int mt = blockIdx.y*16 + wid*2 + ot;
            af[ot] = *(const bf16x8*)(wpad + ((size_t)(mt*6 + kk))*512 + lane*8);
        }
        #pragma unroll
        for (int ot = 0; ot < 2; ++ot)
            #pragma unroll
            for (int tt = 0; tt < 4; ++tt)
                acc[ot][tt] = __builtin_amdgcn_mfma_f32_16x16x32_bf16(af[ot], bt[tt], acc[ot][tt], 0, 0, 0);
    }
    __syncthreads();   // staging dead; reuse LDS as P [t][m] bf16

    // ---- P[t][mloc] = bf16(acc*mask), cvt_pk + u32x2 stores ----
    #pragma unroll
    for (int tt = 0; tt < 4; ++tt) {
        int t = tt*16 + l15;
        float mkv = masks[(size_t)b*NT + tg0 + t];
        #pragma unroll
        for (int ot = 0; ot < 2; ++ot) {
            int mloc = (wid*2 + ot)*16 + (kg << 2);
            f32x4 A = acc[ot][tt];
            *(u32x2*)(&uls[t*PR + (mloc >> 1)]) =
                u32x2{pk_bf16(A[0]*mkv, A[1]*mkv), pk_bf16(A[2]*mkv, A[3]*mkv)};
        }
    }
    __syncthreads();

    // ---- spline: 8 c-channels x 64 t = 512 items, exactly 1 per thread ----
    float lsum = 0.f;
    {
        int cl = tid >> 6, t = tid & 63;
        int c  = blockIdx.y*8 + cl;
        int tg = tg0 + t;
        float m = masks[(size_t)b*NT + tg];

        // x0 flip copy
        float x0v = x[((size_t)b*NC + c)*NT + tg];
        outp[((size_t)b*NC + (NC-1 - c))*NT + tg] = x0v * m;

        float pr[30];
        #pragma unroll
        for (int j = 0; j < 15; ++j) {
            u32 w = uls[t*PR + cl*16 + j];
            pr[2*j]   = bf_lo(w);
            pr[2*j+1] = bf_hi(w);
        }

        float x1 = x[((size_t)b*NC + NHALF + c)*NT + tg];
        float xc = fminf(fmaxf(x1, -5.f), 5.f);

        // exp2 constant-fold: exp(pr*invsq) = exp2(pr * invsq*log2e)
        const float C = 0.10412020934368074f;  // (1/sqrt(192)) * log2(e)
        float ew[10], eh[10], sw = 0.f, sh = 0.f;
        #pragma unroll
        for (int i = 0; i < 10; ++i) { ew[i] = __builtin_amdgcn_exp2f(pr[i]    * C); sw += ew[i]; }
        #pragma unroll
        for (int i = 0; i < 10; ++i) { eh[i] = __builtin_amdgcn_exp2f(pr[10+i] * C); sh += eh[i]; }
        float isw = __builtin_amdgcn_rcpf(sw) * 9.9f;   // step = 0.01 + 9.9*e*inv_s
        float ish = __builtin_amdgcn_rcpf(sh) * 9.9f;

        // fused cumsum + knot selection (forced endpoints preserved)
        float cwp = -5.f, chp = -5.f;
        float icw = -5.f, ich = -5.f, iw = 0.f, ih = 0.f;
        float s0 = 0.f, s1 = pr[20], f0 = 1.f, f9 = 0.f;
        #pragma unroll
        for (int i = 0; i < 10; ++i) {
            float stepw = 0.01f + ew[i]*isw;
            float steph = 0.01f + eh[i]*ish;
            if (i == 9) { stepw = 5.f - cwp; steph = 5.f - chp; }  // forced cw[10]=5
            if (i == 0) {
                iw = stepw; ih = steph;
            } else {
                bool ge = (xc >= cwp);
                icw = ge ? cwp   : icw;
                iw  = ge ? stepw : iw;
                ich = ge ? chp   : ich;
                ih  = ge ? steph : ih;
                s0  = ge ? pr[19+i] : s0;
                if (i <= 8) s1 = ge ? pr[20+i] : s1;
                f0  = ge ? 0.f : f0;
                if (i == 9) f9 = ge ? 1.f : 0.f;
            }
            cwp += stepw; chp += steph;
        }
        float d0 = (f0 != 0.f) ? 1.f : 0.001f + softplus_fast(s0);
        float d1 = (f9 != 0.f) ? 1.f : 0.001f + softplus_fast(s1);

        float rw    = __builtin_amdgcn_rcpf(iw);
        float dlt   = ih * rw;
        float theta = (xc - icw) * rw;
        float t1m   = theta * (1.f - theta);
        float den   = dlt + (d0 + d1 - 2.f*dlt) * t1m;
        float rden  = __builtin_amdgcn_rcpf(den);
        float num   = ih * (dlt*theta*theta + d0*t1m);
        float outv  = ich + num * rden;
        float omt   = 1.f - theta;
        float dnum  = dlt*dlt*(d1*theta*theta + 2.f*dlt*t1m + d0*omt*omt);
        float lad   = __logf(dnum * rden * rden);
        bool inside = (x1 >= -5.f) && (x1 <= 5.f);
        float xout  = inside ? outv : x1;
        float ladv  = inside ? lad : 0.f;
        outp[((size_t)b*NC + (NHALF-1 - c))*NT + tg] = xout * m;
        lsum = ladv * m;
    }

    // ---- wave-shuffle reduction, then 8-way cross-wave sum ----
    #pragma unroll
    for (int off = 32; off > 0; off >>= 1)
        lsum += __shfl_down(lsum, off, 64);
    if (lane == 0) red8[wid] = lsum;
    __syncthreads();
    if (tid == 0) {
        float s = 0.f;
        #pragma unroll
        for (int i = 0; i < 8; ++i) s += red8[i];
        partial[(size_t)b*384 + th*192 + blockIdx.y*16 + blockIdx.x] = s;
    }
}

__global__ __launch_bounds__(256) void logdet_reduce_kernel(
    const float* __restrict__ partial, float* __restrict__ outp)
{
    __shared__ float red[256];
    const int b = blockIdx.x;
    const int tid = threadIdx.x;
    float s = 0.f;
    for (int i = tid; i < 384; i += 256) s += partial[(size_t)b*384 + i];
    red[tid] = s;
    __syncthreads();
    for (int st = 128; st > 0; st >>= 1) {
        if (tid < st) red[tid] += red[tid + st];
        __syncthreads();
    }
    if (tid == 0) outp[(size_t)OUT_ELEMS + b] = red[0];
}

extern "C" void kernel_launch(void* const* d_in, const int* in_sizes, int n_in,
                              void* d_out, int out_size, void* d_ws, size_t ws_size,
                              hipStream_t stream) {
    const float* x     = (const float*)d_in[0];
    const float* cond  = (const float*)d_in[1];
    const float* masks = (const float*)d_in[2];
    const float* pw    = (const float*)d_in[3];
    const float* pb    = (const float*)d_in[4];
    const float* w1    = (const float*)d_in[5];
    const float* b1    = (const float*)d_in[6];
    const float* g1    = (const float*)d_in[7];
    const float* bb1   = (const float*)d_in[8];
    const float* m1    = (const float*)d_in[9];
    const float* v1    = (const float*)d_in[10];
    const float* w2    = (const float*)d_in[11];
    const float* b2    = (const float*)d_in[12];
    const float* g2    = (const float*)d_in[13];
    const float* bb2   = (const float*)d_in[14];
    const float* m2    = (const float*)d_in[15];
    const float* v2    = (const float*)d_in[16];
    const float* pjw   = (const float*)d_in[17];
    const float* pjb   = (const float*)d_in[18];

    float* out = (float*)d_out;
    char* wsb = (char*)d_ws;
    u32*   hidB0   = (u32*)wsb;                                    //  6,291,456 B
    u32*   hidB1   = (u32*)(wsb + 6291456);                        //  6,291,456 B
    u16*   wbf     = (u16*)(wsb + 12582912);                       //  2,101,248 B
    float* pjb_pad = (float*)(wsb + 12582912 + 2101248);           //     12,288 B
    float* partial = (float*)(wsb + 12582912 + 2101248 + 12288);   //     16,384 B

    dim3 blk(256);

    wconv_kernel<<<dim3((WT2 + 3072 + 255)/256), blk, 0, stream>>>(
        w1, w2, pjw, pjb, pw, wbf, pjb_pad);

    const u16* preswz = wbf + W1N + W2N + PADN;
    prenet_mfma_kernel<<<dim3(64,1,8), blk, 0, stream>>>(
        x, cond, preswz, pb, masks, hidB0);

    dim3 grid_r(64, 1, 8);
    {
        resblock_kernel<1><<<grid_r, blk, 0, stream>>>(hidB0, hidB1, wbf, wbf + W1N, masks,
            b1, g1, bb1, m1, v1, b2, g2, bb2, m2, v2);
    }
    {
        const u16* w1l = wbf + (size_t)1*110592;
        const u16* w2l = wbf + W1N + (size_t)1*36864;
        resblock_kernel<3><<<grid_r, blk, 0, stream>>>(hidB1, hidB0, w1l, w2l, masks,
            b1+NC, g1+NC, bb1+NC, m1+NC, v1+NC, b2+NC, g2+NC, bb2+NC, m2+NC, v2+NC);
    }
    {
        const u16* w1l = wbf + (size_t)2*110592;
        const u16* w2l = wbf + W1N + (size_t)2*36864;
        resblock_kernel<9><<<grid_r, blk, 0, stream>>>(hidB0, hidB1, w1l, w2l, masks,
            b1+2*NC, g1+2*NC, bb1+2*NC, m1+2*NC, v1+2*NC,
            b2+2*NC, g2+2*NC, bb2+2*NC, m2+2*NC, v2+2*NC);
    }

    const u16* pjwpad = wbf + W1N + W2N;
    proj_spline_mfma_kernel<<<dim3(16,12,16), dim3(512), 0, stream>>>(
        hidB1, pjwpad, pjb_pad, x, masks, out, partial);

    logdet_reduce_kernel<<<dim3(8), blk, 0, stream>>>(partial, out);
}

// Round 29
// 104.197 us; speedup vs baseline: 1.0723x; 1.0101x over previous
//
#include <hip/hip_runtime.h>
#include <math.h>

#define NB 8
#define NC 192
#define NT 2048
#define NHALF 96
#define NP 29
#define OUT_ELEMS (NB*NC*NT)
#define KP 100    // staging LDS row stride in dwords (200 bf16, 192 used)
#define PR 129    // P LDS row stride in dwords ([t][m] bf16, 256 m + pad)

typedef short bf16x8 __attribute__((ext_vector_type(8)));
typedef float f32x4 __attribute__((ext_vector_type(4)));
typedef unsigned int u32x2 __attribute__((ext_vector_type(2)));
typedef unsigned int u32x4 __attribute__((ext_vector_type(4)));
typedef unsigned short u16;
typedef unsigned int u32;

__device__ __forceinline__ u16 f2bf(float f) {
    u32 u = __builtin_bit_cast(u32, f);
    u += 0x7fffu + ((u >> 16) & 1u);
    return (u16)(u >> 16);
}
// packed f32 pair -> 2x bf16 in one instruction (RNE, same as f2bf)
__device__ __forceinline__ u32 pk_bf16(float lo, float hi) {
    u32 r;
    asm("v_cvt_pk_bf16_f32 %0, %1, %2" : "=v"(r) : "v"(lo), "v"(hi));
    return r;
}
__device__ __forceinline__ float bf_lo(u32 w) { return __builtin_bit_cast(float, w << 16); }
__device__ __forceinline__ float bf_hi(u32 w) { return __builtin_bit_cast(float, w & 0xffff0000u); }
__device__ __forceinline__ float softplus_fast(float v) {
    return (v > 20.0f) ? v : __logf(1.0f + __expf(v));
}
// mish(x) = x*tanh(softplus(x)) = x*(s^2-1)/(s^2+1), s = 1+e^x
__device__ __forceinline__ float mishf(float v) {
    if (v > 20.0f) return v;
    float s = 1.0f + __expf(v);
    float s2 = s * s;
    return v * (s2 - 1.0f) / (s2 + 1.0f);
}

// ---------- weight convert + fragment swizzle ----------
// swz[tile*512 + lane*8 + e] = W[m][k], m = mt*16+(lane&15), k = kk*32+(lane>>4)*8+e
#define W1N 331776   // 3*3*36864
#define W2N 110592   // 3*36864
#define PADN 589824  // 1152*512
#define PREN 18432   // 36*512
#define WT2 (W1N+W2N+PADN+PREN)
__global__ __launch_bounds__(256) void wconv_kernel(
    const float* __restrict__ w1, const float* __restrict__ w2,
    const float* __restrict__ pjw, const float* __restrict__ pjb,
    const float* __restrict__ pw,
    u16* __restrict__ outw, float* __restrict__ pjb_pad)
{
    int i = blockIdx.x*256 + threadIdx.x;
    if (i < WT2) {
        float v;
        if (i < W1N) {
            int s = i / 110592, r = i % 110592;
            int j = r / 36864, q = r % 36864;
            int tile = q >> 9, lane = (q >> 3) & 63, e = q & 7;
            int mt = tile / 6, kk = tile % 6;
            int m = mt*16 + (lane & 15);
            int k = kk*32 + (lane >> 4)*8 + e;
            v = w1[(((size_t)s*192 + m)*192 + k)*3 + j];
        } else if (i < W1N + W2N) {
            int q0 = i - W1N;
            int s = q0 / 36864, q = q0 % 36864;
            int tile = q >> 9, lane = (q >> 3) & 63, e = q & 7;
            int mt = tile / 6, kk = tile % 6;
            int m = mt*16 + (lane & 15);
            int k = kk*32 + (lane >> 4)*8 + e;
            v = w2[((size_t)s*192 + m)*192 + k];
        } else if (i < W1N + W2N + PADN) {
            int q = i - W1N - W2N;
            int tile = q >> 9, lane = (q >> 3) & 63, e = q & 7;
            int mt = tile / 6, kk = tile % 6;
            int m = mt*16 + (lane & 15);            // 0..3071
            int k = kk*32 + (lane >> 4)*8 + e;
            int c = m >> 5, p = m & 31;
            v = (p < NP) ? pjw[((size_t)(c*NP + p))*192 + k] : 0.f;
        } else {
            int q = i - W1N - W2N - PADN;
            int tile = q >> 9, lane = (q >> 3) & 63, e = q & 7;
            int mt = tile / 3, kk = tile % 3;
            int m = mt*16 + (lane & 15);            // 0..191
            int k = kk*32 + (lane >> 4)*8 + e;      // 0..95
            v = pw[(size_t)m*96 + k];
        }
        outw[i] = f2bf(v);
    } else if (i < WT2 + 3072) {
        int mp = i - WT2;
        int c = mp >> 5, p = mp & 31;
        pjb_pad[mp] = (p < NP) ? pjb[c*NP + p] : 0.f;
    }
}

// ---------- prenet MFMA: hidB = bf16((W x0 + bias + cond) * mask) ----------
__global__ __launch_bounds__(256) void prenet_mfma_kernel(
    const float* __restrict__ x, const float* __restrict__ cond,
    const u16* __restrict__ wps, const float* __restrict__ bias,
    const float* __restrict__ masks, u32* __restrict__ hidB)
{
    __shared__ u32 sm[32 * 52];
    const int tid = threadIdx.x, lane = tid & 63, wid = tid >> 6;
    const int b = blockIdx.z, tg0 = blockIdx.x * 32;
    const int l15 = lane & 15, kg = lane >> 4;

    for (int idx = tid; idx < 48*32; idx += 256) {
        int c2 = idx >> 5, tl = idx & 31;
        const float* p = x + ((size_t)b*NC + 2*c2)*NT + tg0 + tl;
        sm[tl*52 + c2] = pk_bf16(p[0], p[NT]);
    }
    __syncthreads();

    // bias-init accumulators (MFMA C-in carries bias)
    f32x4 acc[3][2];
    #pragma unroll
    for (int ot = 0; ot < 3; ++ot) {
        f32x4 bi = *(const f32x4*)(bias + (wid*3 + ot)*16 + (kg << 2));
        acc[ot][0] = bi; acc[ot][1] = bi;
    }
    const char* smb = (const char*)sm;

    for (int kk = 0; kk < 3; ++kk) {
        int k0 = kk*32 + kg*8;
        bf16x8 b0 = *(const bf16x8*)(smb + (size_t)l15*208 + k0*2);
        bf16x8 b1f = *(const bf16x8*)(smb + (size_t)(l15+16)*208 + k0*2);
        bf16x8 af[3];
        #pragma unroll
        for (int ot = 0; ot < 3; ++ot) {
            int mt = wid*3 + ot;
            af[ot] = *(const bf16x8*)(wps + ((size_t)(mt*3 + kk))*512 + lane*8);
        }
        #pragma unroll
        for (int ot = 0; ot < 3; ++ot) {
            acc[ot][0] = __builtin_amdgcn_mfma_f32_16x16x32_bf16(af[ot], b0, acc[ot][0], 0, 0, 0);
            acc[ot][1] = __builtin_amdgcn_mfma_f32_16x16x32_bf16(af[ot], b1f, acc[ot][1], 0, 0, 0);
        }
    }

    #pragma unroll
    for (int ot = 0; ot < 3; ++ot) {
        int m = (wid*3 + ot)*16 + (kg << 2);
        #pragma unroll
        for (int tt = 0; tt < 2; ++tt) {
            int t = tg0 + tt*16 + l15;
            float mv = masks[(size_t)b*NT + t];
            f32x4 A = acc[ot][tt];
            f32x4 o;
            #pragma unroll
            for (int r = 0; r < 4; ++r)
                o[r] = (A[r] + cond[((size_t)b*NC + m + r)*NT + t]) * mv;
            *(u32x2*)(hidB + ((size_t)b*NT + t)*96 + (m >> 1)) =
                u32x2{pk_bf16(o[0], o[1]), pk_bf16(o[2], o[3])};
        }
    }
}

// ---------- fused residual block (TT=32), bf16 masked trunk ----------
// hidM_new = hidM_old + mask * BN2(mish(conv2(BN1(mish(conv1(hidM))))))
// old value comes from sm1 (already staged) -- no global trunk RMW.
template<int DIL>
__global__ __launch_bounds__(256) void resblock_kernel(
    const u32* __restrict__ hidBin, u32* __restrict__ hidBout,
    const u16* __restrict__ w1s, const u16* __restrict__ w2s,
    const float* __restrict__ masks,
    const float* __restrict__ b1v, const float* __restrict__ g1v, const float* __restrict__ bb1v,
    const float* __restrict__ bm1v, const float* __restrict__ bv1v,
    const float* __restrict__ b2v, const float* __restrict__ g2v, const float* __restrict__ bb2v,
    const float* __restrict__ bm2v, const float* __restrict__ bv2v)
{
    constexpr int ROWS = 32 + 2*DIL;
    __shared__ u32 sm1[ROWS * KP];
    __shared__ u32 sm2[32 * KP];
    const int tid = threadIdx.x, lane = tid & 63, wid = tid >> 6;
    const int b = blockIdx.z, tg0 = blockIdx.x * 32;
    const int l15 = lane & 15, kg = lane >> 4;

    // stage pre-masked bf16 rows from hidBin: pure 16B copies
    for (int it = tid; it < ROWS*24; it += 256) {
        int row = it / 24, q = it - row*24;
        int t = tg0 + row - DIL;
        u32x4 v = u32x4{0,0,0,0};
        if (t >= 0 && t < NT)
            v = *(const u32x4*)(hidBin + ((size_t)b*NT + t)*96 + q*4);
        *(u32x4*)(&sm1[row*KP + q*4]) = v;
    }
    __syncthreads();

    // GEMM1 (bias-init acc), A-prefetch across 18 iters
    f32x4 acc[3][2];
    #pragma unroll
    for (int ot = 0; ot < 3; ++ot) {
        f32x4 bi = *(const f32x4*)(b1v + (wid*3 + ot)*16 + (kg << 2));
        acc[ot][0] = bi; acc[ot][1] = bi;
    }
    const char* smb1 = (const char*)sm1;

    bf16x8 afc[3], afn[3];
    #pragma unroll
    for (int ot = 0; ot < 3; ++ot)
        afc[ot] = *(const bf16x8*)(w1s + ((size_t)((wid*3 + ot)*6))*512 + lane*8);

    #pragma unroll
    for (int it = 0; it < 18; ++it) {
        const int j = it / 6, kk = it % 6;
        if (it + 1 < 18) {
            const int jn = (it + 1) / 6, kkn = (it + 1) % 6;
            const u16* wn = w1s + (size_t)jn * 36864;
            #pragma unroll
            for (int ot = 0; ot < 3; ++ot)
                afn[ot] = *(const bf16x8*)(wn + ((size_t)((wid*3 + ot)*6 + kkn))*512 + lane*8);
        }
        int k0 = kk*32 + kg*8;
        bf16x8 b0  = *(const bf16x8*)(smb1 + (size_t)(l15 + j*DIL)*400 + k0*2);
        bf16x8 b1f = *(const bf16x8*)(smb1 + (size_t)(l15 + 16 + j*DIL)*400 + k0*2);
        #pragma unroll
        for (int ot = 0; ot < 3; ++ot) {
            acc[ot][0] = __builtin_amdgcn_mfma_f32_16x16x32_bf16(afc[ot], b0,  acc[ot][0], 0, 0, 0);
            acc[ot][1] = __builtin_amdgcn_mfma_f32_16x16x32_bf16(afc[ot], b1f, acc[ot][1], 0, 0, 0);
        }
        #pragma unroll
        for (int ot = 0; ot < 3; ++ot) afc[ot] = afn[ot];
    }

    // epilogue1: tmp = BN1(mish(acc)) -> sm2 [t][k] bf16 pairs
    #pragma unroll
    for (int ot = 0; ot < 3; ++ot) {
        int m = (wid*3 + ot)*16 + (kg << 2);
        f32x4 g4 = *(const f32x4*)(g1v + m);
        f32x4 bb4 = *(const f32x4*)(bb1v + m);
        f32x4 bm4 = *(const f32x4*)(bm1v + m);
        f32x4 bv4 = *(const f32x4*)(bv1v + m);
        #pragma unroll
        for (int tt = 0; tt < 2; ++tt) {
            int tl = tt*16 + l15;
            f32x4 A = acc[ot][tt];
            float vr[4];
            #pragma unroll
            for (int r = 0; r < 4; ++r) {
                float v = mishf(A[r]);
                vr[r] = (v - bm4[r]) * (g4[r] * rsqrtf(bv4[r] + 1e-5f)) + bb4[r];
            }
            *(u32x2*)(&sm2[tl*KP + (m >> 1)]) = u32x2{pk_bf16(vr[0], vr[1]), pk_bf16(vr[2], vr[3])};
        }
    }
    __syncthreads();

    // GEMM2 (bias-init acc), A-prefetch across 6 iters
    f32x4 acc2[3][2];
    #pragma unroll
    for (int ot = 0; ot < 3; ++ot) {
        f32x4 bi = *(const f32x4*)(b2v + (wid*3 + ot)*16 + (kg << 2));
        acc2[ot][0] = bi; acc2[ot][1] = bi;
    }
    const char* smb2 = (const char*)sm2;

    #pragma unroll
    for (int ot = 0; ot < 3; ++ot)
        afc[ot] = *(const bf16x8*)(w2s + ((size_t)((wid*3 + ot)*6))*512 + lane*8);

    #pragma unroll
    for (int kk = 0; kk < 6; ++kk) {
        if (kk + 1 < 6) {
            #pragma unroll
            for (int ot = 0; ot < 3; ++ot)
                afn[ot] = *(const bf16x8*)(w2s + ((size_t)((wid*3 + ot)*6 + kk + 1))*512 + lane*8);
        }
        int k0 = kk*32 + kg*8;
        bf16x8 b0  = *(const bf16x8*)(smb2 + (size_t)l15*400 + k0*2);
        bf16x8 b1f = *(const bf16x8*)(smb2 + (size_t)(l15+16)*400 + k0*2);
        #pragma unroll
        for (int ot = 0; ot < 3; ++ot) {
            acc2[ot][0] = __builtin_amdgcn_mfma_f32_16x16x32_bf16(afc[ot], b0,  acc2[ot][0], 0, 0, 0);
            acc2[ot][1] = __builtin_amdgcn_mfma_f32_16x16x32_bf16(afc[ot], b1f, acc2[ot][1], 0, 0, 0);
        }
        #pragma unroll
        for (int ot = 0; ot < 3; ++ot) afc[ot] = afn[ot];
    }

    // epilogue2: hidBout = bf16(old(sm1) + mask * BN2(mish(acc2)))
    #pragma unroll
    for (int ot = 0; ot < 3; ++ot) {
        int m = (wid*3 + ot)*16 + (kg << 2);
        f32x4 g4 = *(const f32x4*)(g2v + m);
        f32x4 bb4 = *(const f32x4*)(bb2v + m);
        f32x4 bm4 = *(const f32x4*)(bm2v + m);
        f32x4 bv4 = *(const f32x4*)(bv2v + m);
        #pragma unroll
        for (int tt = 0; tt < 2; ++tt) {
            int tl = tt*16 + l15;
            int t = tg0 + tl;
            float mv = masks[(size_t)b*NT + t];
            f32x4 A = acc2[ot][tt];
            u32x2 ow = *(const u32x2*)(&sm1[(tl + DIL)*KP + (m >> 1)]);
            float old0 = bf_lo(ow[0]), old1 = bf_hi(ow[0]);
            float old2 = bf_lo(ow[1]), old3 = bf_hi(ow[1]);
            float nv[4];
            {
                float v0 = mishf(A[0]), v1 = mishf(A[1]), v2 = mishf(A[2]), v3 = mishf(A[3]);
                nv[0] = old0 + mv * ((v0 - bm4[0]) * (g4[0] * rsqrtf(bv4[0] + 1e-5f)) + bb4[0]);
                nv[1] = old1 + mv * ((v1 - bm4[1]) * (g4[1] * rsqrtf(bv4[1] + 1e-5f)) + bb4[1]);
                nv[2] = old2 + mv * ((v2 - bm4[2]) * (g4[2] * rsqrtf(bv4[2] + 1e-5f)) + bb4[2]);
                nv[3] = old3 + mv * ((v3 - bm4[3]) * (g4[3] * rsqrtf(bv4[3] + 1e-5f)) + bb4[3]);
            }
            *(u32x2*)(hidBout + ((size_t)b*NT + t)*96 + (m >> 1)) =
                u32x2{pk_bf16(nv[0], nv[1]), pk_bf16(nv[2], nv[3])};
        }
    }
}

// ---------- fused proj GEMM (M=256/block, 8 waves x 2mt, A-prefetch) + RQ spline ----------
// grid (16 t-tiles, 12 m-blocks(=8c each), 16 units(b,th)), block 512
__global__ __launch_bounds__(512) void proj_spline_mfma_kernel(
    const u32* __restrict__ hidB, const u16* __restrict__ wpad,
    const float* __restrict__ pjb_pad, const float* __restrict__ x,
    const float* __restrict__ masks, float* __restrict__ outp,
    float* __restrict__ partial)
{
    __shared__ u32 uls[64*PR];   // union: staging [64][KP] then P [64 t][258 u16]
    __shared__ float red8[8];
    const int tid  = threadIdx.x;
    const int lane = tid & 63;
    const int wid  = tid >> 6;   // 0..7
    const int z  = blockIdx.z;
    const int b  = z >> 1, th = z & 1;
    const int tg0 = th*1024 + blockIdx.x*64;
    const int l15 = lane & 15;
    const int kg  = lane >> 4;

    // ---- stage B tile: pre-masked bf16 from hidB, pure 16B copies ----
    for (int it = tid; it < 64*24; it += 512) {
        int row = it / 24, q = it - row*24;
        u32x4 v = *(const u32x4*)(hidB + ((size_t)b*NT + tg0 + row)*96 + q*4);
        *(u32x4*)(&uls[row*KP + q*4]) = v;
    }
    __syncthreads();

    // ---- GEMM: 256 m x 64 t x 192 k, 8 waves each own 2 mt, A-prefetch ----
    f32x4 acc[2][4];   // [ot][tt]
    #pragma unroll
    for (int ot = 0; ot < 2; ++ot) {
        f32x4 pb = *(const f32x4*)(pjb_pad + blockIdx.y*256 + (wid*2 + ot)*16 + (kg << 2));
        #pragma unroll
        for (int tt = 0; tt < 4; ++tt) acc[ot][tt] = pb;
    }
    const char* smb = (const char*)uls;
    const int mtb = blockIdx.y*16 + wid*2;

    bf16x8 afc[2], afn[2];
    #pragma unroll
    for (int ot = 0; ot < 2; ++ot)
        afc[ot] = *(const bf16x8*)(wpad + ((size_t)((mtb + ot)*6))*512 + lane*8);

    #pragma unroll
    for (int kk = 0; kk < 6; ++kk) {
        if (kk + 1 < 6) {
            #pragma unroll
            for (int ot = 0; ot < 2; ++ot)
                afn[ot] = *(const bf16x8*)(wpad + ((size_t)((mtb + ot)*6 + kk + 1))*512 + lane*8);
        }
        int k0 = kk*32 + kg*8;
        bf16x8 bt[4];
        #pragma unroll
        for (int tt = 0; tt < 4; ++tt)
            bt[tt] = *(const bf16x8*)(smb + (size_t)(tt*16 + l15)*400 + k0*2);
        #pragma unroll
        for (int ot = 0; ot < 2; ++ot)
            #pragma unroll
            for (int tt = 0; tt < 4; ++tt)
                acc[ot][tt] = __builtin_amdgcn_mfma_f32_16x16x32_bf16(afc[ot], bt[tt], acc[ot][tt], 0, 0, 0);
        #pragma unroll
        for (int ot = 0; ot < 2; ++ot) afc[ot] = afn[ot];
    }
    __syncthreads();   // staging dead; reuse LDS as P [t][m] bf16

    // ---- P[t][mloc] = bf16(acc*mask), cvt_pk + u32x2 stores ----
    #pragma unroll
    for (int tt = 0; tt < 4; ++tt) {
        int t = tt*16 + l15;
        float mkv = masks[(size_t)b*NT + tg0 + t];
        #pragma unroll
        for (int ot = 0; ot < 2; ++ot) {
            int mloc = (wid*2 + ot)*16 + (kg << 2);
            f32x4 A = acc[ot][tt];
            *(u32x2*)(&uls[t*PR + (mloc >> 1)]) =
                u32x2{pk_bf16(A[0]*mkv, A[1]*mkv), pk_bf16(A[2]*mkv, A[3]*mkv)};
        }
    }
    __syncthreads();

    // ---- spline: 8 c-channels x 64 t = 512 items, exactly 1 per thread ----
    float lsum = 0.f;
    {
        int cl = tid >> 6, t = tid & 63;
        int c  = blockIdx.y*8 + cl;
        int tg = tg0 + t;
        float m = masks[(size_t)b*NT + tg];

        // x0 flip copy
        float x0v = x[((size_t)b*NC + c)*NT + tg];
        outp[((size_t)b*NC + (NC-1 - c))*NT + tg] = x0v * m;

        float pr[30];
        #pragma unroll
        for (int j = 0; j < 15; ++j) {
            u32 w = uls[t*PR + cl*16 + j];
            pr[2*j]   = bf_lo(w);
            pr[2*j+1] = bf_hi(w);
        }

        float x1 = x[((size_t)b*NC + NHALF + c)*NT + tg];
        float xc = fminf(fmaxf(x1, -5.f), 5.f);

        // exp2 constant-fold: exp(pr*invsq) = exp2(pr * invsq*log2e)
        const float C = 0.10412020934368074f;  // (1/sqrt(192)) * log2(e)
        float ew[10], eh[10], sw = 0.f, sh = 0.f;
        #pragma unroll
        for (int i = 0; i < 10; ++i) { ew[i] = __builtin_amdgcn_exp2f(pr[i]    * C); sw += ew[i]; }
        #pragma unroll
        for (int i = 0; i < 10; ++i) { eh[i] = __builtin_amdgcn_exp2f(pr[10+i] * C); sh += eh[i]; }
        float isw = __builtin_amdgcn_rcpf(sw) * 9.9f;   // step = 0.01 + 9.9*e*inv_s
        float ish = __builtin_amdgcn_rcpf(sh) * 9.9f;

        // fused cumsum + knot selection (forced endpoints preserved)
        float cwp = -5.f, chp = -5.f;
        float icw = -5.f, ich = -5.f, iw = 0.f, ih = 0.f;
        float s0 = 0.f, s1 = pr[20], f0 = 1.f, f9 = 0.f;
        #pragma unroll
        for (int i = 0; i < 10; ++i) {
            float stepw = 0.01f + ew[i]*isw;
            float steph = 0.01f + eh[i]*ish;
            if (i == 9) { stepw = 5.f - cwp; steph = 5.f - chp; }  // forced cw[10]=5
            if (i == 0) {
                iw = stepw; ih = steph;
            } else {
                bool ge = (xc >= cwp);
                icw = ge ? cwp   : icw;
                iw  = ge ? stepw : iw;
                ich = ge ? chp   : ich;
                ih  = ge ? steph : ih;
                s0  = ge ? pr[19+i] : s0;
                if (i <= 8) s1 = ge ? pr[20+i] : s1;
                f0  = ge ? 0.f : f0;
                if (i == 9) f9 = ge ? 1.f : 0.f;
            }
            cwp += stepw; chp += steph;
        }
        float d0 = (f0 != 0.f) ? 1.f : 0.001f + softplus_fast(s0);
        float d1 = (f9 != 0.f) ? 1.f : 0.001f + softplus_fast(s1);

        float rw    = __builtin_amdgcn_rcpf(iw);
        float dlt   = ih * rw;
        float theta = (xc - icw) * rw;
        float t1m   = theta * (1.f - theta);
        float den   = dlt + (d0 + d1 - 2.f*dlt) * t1m;
        float rden  = __builtin_amdgcn_rcpf(den);
        float num   = ih * (dlt*theta*theta + d0*t1m);
        float outv  = ich + num * rden;
        float omt   = 1.f - theta;
        float dnum  = dlt*dlt*(d1*theta*theta + 2.f*dlt*t1m + d0*omt*omt);
        float lad   = __logf(dnum * rden * rden);
        bool inside = (x1 >= -5.f) && (x1 <= 5.f);
        float xout  = inside ? outv : x1;
        float ladv  = inside ? lad : 0.f;
        outp[((size_t)b*NC + (NHALF-1 - c))*NT + tg] = xout * m;
        lsum = ladv * m;
    }

    // ---- wave-shuffle reduction, then 8-way cross-wave sum ----
    #pragma unroll
    for (int off = 32; off > 0; off >>= 1)
        lsum += __shfl_down(lsum, off, 64);
    if (lane == 0) red8[wid] = lsum;
    __syncthreads();
    if (tid == 0) {
        float s = 0.f;
        #pragma unroll
        for (int i = 0; i < 8; ++i) s += red8[i];
        partial[(size_t)b*384 + th*192 + blockIdx.y*16 + blockIdx.x] = s;
    }
}

__global__ __launch_bounds__(256) void logdet_reduce_kernel(
    const float* __restrict__ partial, float* __restrict__ outp)
{
    __shared__ float red[256];
    const int b = blockIdx.x;
    const int tid = threadIdx.x;
    float s = 0.f;
    for (int i = tid; i < 384; i += 256) s += partial[(size_t)b*384 + i];
    red[tid] = s;
    __syncthreads();
    for (int st = 128; st > 0; st >>= 1) {
        if (tid < st) red[tid] += red[tid + st];
        __syncthreads();
    }
    if (tid == 0) outp[(size_t)OUT_ELEMS + b] = red[0];
}

extern "C" void kernel_launch(void* const* d_in, const int* in_sizes, int n_in,
                              void* d_out, int out_size, void* d_ws, size_t ws_size,
                              hipStream_t stream) {
    const float* x     = (const float*)d_in[0];
    const float* cond  = (const float*)d_in[1];
    const float* masks = (const float*)d_in[2];
    const float* pw    = (const float*)d_in[3];
    const float* pb    = (const float*)d_in[4];
    const float* w1    = (const float*)d_in[5];
    const float* b1    = (const float*)d_in[6];
    const float* g1    = (const float*)d_in[7];
    const float* bb1   = (const float*)d_in[8];
    const float* m1    = (const float*)d_in[9];
    const float* v1    = (const float*)d_in[10];
    const float* w2    = (const float*)d_in[11];
    const float* b2    = (const float*)d_in[12];
    const float* g2    = (const float*)d_in[13];
    const float* bb2   = (const float*)d_in[14];
    const float* m2    = (const float*)d_in[15];
    const float* v2    = (const float*)d_in[16];
    const float* pjw   = (const float*)d_in[17];
    const float* pjb   = (const float*)d_in[18];

    float* out = (float*)d_out;
    char* wsb = (char*)d_ws;
    u32*   hidB0   = (u32*)wsb;                                    //  6,291,456 B
    u32*   hidB1   = (u32*)(wsb + 6291456);                        //  6,291,456 B
    u16*   wbf     = (u16*)(wsb + 12582912);                       //  2,101,248 B
    float* pjb_pad = (float*)(wsb + 12582912 + 2101248);           //     12,288 B
    float* partial = (float*)(wsb + 12582912 + 2101248 + 12288);   //     16,384 B

    dim3 blk(256);

    wconv_kernel<<<dim3((WT2 + 3072 + 255)/256), blk, 0, stream>>>(
        w1, w2, pjw, pjb, pw, wbf, pjb_pad);

    const u16* preswz = wbf + W1N + W2N + PADN;
    prenet_mfma_kernel<<<dim3(64,1,8), blk, 0, stream>>>(
        x, cond, preswz, pb, masks, hidB0);

    dim3 grid_r(64, 1, 8);
    {
        resblock_kernel<1><<<grid_r, blk, 0, stream>>>(hidB0, hidB1, wbf, wbf + W1N, masks,
            b1, g1, bb1, m1, v1, b2, g2, bb2, m2, v2);
    }
    {
        const u16* w1l = wbf + (size_t)1*110592;
        const u16* w2l = wbf + W1N + (size_t)1*36864;
        resblock_kernel<3><<<grid_r, blk, 0, stream>>>(hidB1, hidB0, w1l, w2l, masks,
            b1+NC, g1+NC, bb1+NC, m1+NC, v1+NC, b2+NC, g2+NC, bb2+NC, m2+NC, v2+NC);
    }
    {
        const u16* w1l = wbf + (size_t)2*110592;
        const u16* w2l = wbf + W1N + (size_t)2*36864;
        resblock_kernel<9><<<grid_r, blk, 0, stream>>>(hidB0, hidB1, w1l, w2l, masks,
            b1+2*NC, g1+2*NC, bb1+2*NC, m1+2*NC, v1+2*NC,
            b2+2*NC, g2+2*NC, bb2+2*NC, m2+2*NC, v2+2*NC);
    }

    const u16* pjwpad = wbf + W1N + W2N;
    proj_spline_mfma_kernel<<<dim3(16,12,16), dim3(512), 0, stream>>>(
        hidB1, pjwpad, pjb_pad, x, masks, out, partial);

    logdet_reduce_kernel<<<dim3(8), blk, 0, stream>>>(partial, out);
}